// Round 16
// baseline (214.106 us; speedup 1.0000x reference)
//
#include <hip/hip_runtime.h>
#include <math.h>

// Problem constants
#define QN 4096
#define MN 65536
#define DN 384
#define CN 128
#define NCHUNK 64                 // m-chunks
#define MROWS_PER_CHUNK (MN / NCHUNK)   // 1024
#define MT_PER (MROWS_PER_CHUNK / 64)   // 16 m-tiles (64 rows) per block
// fp4 fragment-major: one fragment block = 64 lanes x 16B = 1024 B
#define FRAG_B 1024
#define GSTRIDE (3 * FRAG_B)            // bytes per 16-row group (3 kc) = 3072
#define TSTRIDE (4 * GSTRIDE)           // bytes per 64-row tile = 12288

typedef __attribute__((ext_vector_type(8))) int i32x8;
typedef __attribute__((ext_vector_type(4))) int i32x4;
typedef __attribute__((ext_vector_type(4))) float f32x4;

// e2m1 fp4 encode (nearest): levels 0,0.5,1,1.5,2,3,4,6; bit3 = sign.
__device__ __forceinline__ unsigned fp4e(float x) {
  const float a = fabsf(x);
  unsigned c = (unsigned)(a >= 0.25f) + (a >= 0.75f) + (a >= 1.25f) +
               (a >= 1.75f) + (a >= 2.5f) + (a >= 3.5f) + (a >= 5.0f);
  return ((x < 0.f) ? 8u : 0u) | c;
}

// ------- Kernel A: L2-normalize rows; BOTH q and m -> fp4 fragment-major ---
// (R15 verbatim — verified absmax 0.0.)
__global__ __launch_bounds__(256) void nrm_kernel(const float* __restrict__ qe,
                                                  const float* __restrict__ me,
                                                  unsigned char* __restrict__ yq,
                                                  unsigned char* __restrict__ ym) {
  const int row = blockIdx.x * 4 + (threadIdx.x >> 6);
  const int lane = threadIdx.x & 63;
  const int isq = (row < QN);
  const int r = isq ? row : row - QN;
  const float* xr = isq ? qe + (size_t)r * DN : me + (size_t)r * DN;
  unsigned char* yb = isq ? yq : ym;
  float2 v[3];
  float ss = 0.f;
#pragma unroll
  for (int i = 0; i < 3; ++i) {
    v[i] = *(const float2*)&xr[lane * 2 + i * 128];
    ss += v[i].x * v[i].x + v[i].y * v[i].y;
  }
#pragma unroll
  for (int m = 1; m < 64; m <<= 1) ss += __shfl_xor(ss, m);
  const float s16 = (16.0f / fmaxf(sqrtf(ss), 1e-8f));
  const int g = r >> 4;
  const int fl = ((lane >> 4) << 4) + (r & 15);   // fragment lane index
#pragma unroll
  for (int i = 0; i < 3; ++i) {
    const unsigned b = fp4e(v[i].x * s16) | (fp4e(v[i].y * s16) << 4);
    yb[((size_t)(g * 3 + i) * 64 + fl) * 16 + (lane & 15)] = (unsigned char)b;
  }
}

// ------- Kernel B: MX fp4xfp4 GEMM, 4-buffer deep prefetch -----------------
// R16: R15 (gemm ~54 µs) still sums MFMA (28.5 µs/CU) + L1-return (20 µs/CU):
// at the fp4 rate a cluster is only ~268 cyc while per-wave L1 delivery of a
// 3KB half-tile takes ~380+latency. Deepen to 4 buffers (P0/P1 ct0, Q0/Q1
// ct1), unroll-2 named-set rotation (no copies, rule #20): every load-group
// now has ~2.5 clusters (~670 cyc) of covering MFMA. +6 shells (~+24-48
// VGPR from 88) — residency >= 3 blocks/CU, plus 8 blocks/CU of cross-wave
// TLP. Zero barriers, zero LDS in the loop (R15 structure).
__global__ __launch_bounds__(256, 2) void gemm_max_kernel(
    const unsigned char* __restrict__ qn4, const unsigned char* __restrict__ mn4,
    float* __restrict__ pmax) {
  __shared__ float smax[2][128];

  const int tid = threadIdx.x;
  const int wave = tid >> 6, lane = tid & 63;
  const int wr = wave >> 1, wc = wave & 1;   // waves: 2x2 over 128q x 64m
  const int quad = lane >> 4, l16 = lane & 15;

  // --- XCD-partitioned bijective swizzle (HW assigns XCD = linear id % 8) ---
  const int bid = blockIdx.y * gridDim.x + blockIdx.x;  // linear dispatch id
  const int xcd = bid & 7;
  const int j = bid >> 3;                    // 0..255 within this XCD
  const int ychunk = (xcd << 3) | (j >> 5);  // 8 m-chunks per XCD
  const int qrow0 = (j & 31) * 128;          // x sweeps fastest
  const int mchunk0 = ychunk * MROWS_PER_CHUNK;

  float rmax[16];
#pragma unroll
  for (int i = 0; i < 16; ++i) rmax[i] = -3.0e38f;

  // ---- A fragments direct from global (fragment-major, L2-resident) -------
  const int gq0 = (qrow0 >> 4) + wr * 4;     // 16-row group of rt=0
  i32x8 afr[3][4];
#pragma unroll
  for (int kc = 0; kc < 3; ++kc)
#pragma unroll
    for (int rt = 0; rt < 4; ++rt) {
      afr[kc][rt] = (i32x8){0, 0, 0, 0, 0, 0, 0, 0};
      i32x4 t = *(const i32x4*)(qn4 +
          ((size_t)((gq0 + rt) * 3 + kc) * 64 + lane) * 16);
      afr[kc][rt][0] = t[0]; afr[kc][rt][1] = t[1];
      afr[kc][rt][2] = t[2]; afr[kc][rt][3] = t[3];
    }

  // --- per-wave fragment-major fp4 B pointers (ct0 -> g0, ct1 -> g0+1) -----
  const int g0 = (mchunk0 >> 4) + wc * 2;
  const unsigned char* bp0 = mn4 + ((size_t)g0 * 3 * 64 + lane) * 16;  // ct0
  const unsigned char* bp1 = bp0 + GSTRIDE;                            // ct1

  i32x8 P0[3], P1[3], Q0[3], Q1[3];
#pragma unroll
  for (int kc = 0; kc < 3; ++kc) {
    P0[kc] = (i32x8){0, 0, 0, 0, 0, 0, 0, 0};
    P1[kc] = (i32x8){0, 0, 0, 0, 0, 0, 0, 0};
    Q0[kc] = (i32x8){0, 0, 0, 0, 0, 0, 0, 0};
    Q1[kc] = (i32x8){0, 0, 0, 0, 0, 0, 0, 0};
  }

#define LOADH(DST, PTR)                                   \
  do {                                                    \
    _Pragma("unroll") for (int kc = 0; kc < 3; ++kc) {    \
      i32x4 t = *(const i32x4*)((PTR) + kc * FRAG_B);     \
      DST[kc][0] = t[0]; DST[kc][1] = t[1];               \
      DST[kc][2] = t[2]; DST[kc][3] = t[3];               \
    }                                                     \
  } while (0)

#define CLUSTER(BF)                                                           \
  do {                                                                        \
    f32x4 acc[4];                                                             \
    _Pragma("unroll") for (int rt = 0; rt < 4; ++rt)                          \
        acc[rt] = (f32x4){0.f, 0.f, 0.f, 0.f};                                \
    __builtin_amdgcn_s_setprio(1);                                            \
    _Pragma("unroll") for (int kc = 0; kc < 3; ++kc)                          \
        _Pragma("unroll") for (int rt = 0; rt < 4; ++rt)                      \
            acc[rt] = __builtin_amdgcn_mfma_scale_f32_16x16x128_f8f6f4(       \
                afr[kc][rt], BF[kc], acc[rt], 4, 4,   /* A fp4, B fp4 */      \
                0, 0x7b7b7b7b, 0, 0x7b7b7b7b);        /* scales 2^-4 */       \
    __builtin_amdgcn_s_setprio(0);                                            \
    _Pragma("unroll") for (int rt = 0; rt < 4; ++rt)                          \
        _Pragma("unroll") for (int r = 0; r < 4; ++r)                         \
            rmax[rt * 4 + r] = fmaxf(rmax[rt * 4 + r], acc[rt][r]);           \
  } while (0)

// Body for tile MT with named buffer sets (P holds ct0(MT), Q holds ct1(MT)).
// Loads issued here: ct1(MT+1) -> QN (consumed next iter, ~2.5 clusters
// away); ct0(MT+2) -> P (P just consumed; used 2 iters away).
#define GEMM_BODY(MT, P, PN, Q, QN)                                           \
  do {                                                                        \
    if ((MT) + 1 < MT_PER) { LOADH(QN, bp1); bp1 += TSTRIDE; }                \
    __builtin_amdgcn_sched_barrier(0);                                        \
    CLUSTER(P);                                                               \
    __builtin_amdgcn_sched_barrier(0);                                        \
    if ((MT) + 2 < MT_PER) { LOADH(P, bp0); bp0 += TSTRIDE; }                 \
    __builtin_amdgcn_sched_barrier(0);                                        \
    CLUSTER(Q);                                                               \
    __builtin_amdgcn_sched_barrier(0);                                        \
  } while (0)

  // prologue: ct0(0)->P0, ct1(0)->Q0, ct0(1)->P1 (9 loads in flight)
  LOADH(P0, bp0);
  LOADH(Q0, bp1);
  bp1 += TSTRIDE;
  LOADH(P1, bp0 + TSTRIDE);
  bp0 += 2 * TSTRIDE;

#pragma unroll 1
  for (int mt = 0; mt < MT_PER; mt += 2) {
    GEMM_BODY(mt, P0, P1, Q0, Q1);
    GEMM_BODY(mt + 1, P1, P0, Q1, Q0);
  }
#undef GEMM_BODY
#undef CLUSTER
#undef LOADH

#pragma unroll
  for (int i = 0; i < 16; ++i) {
    float v = rmax[i];
    v = fmaxf(v, __shfl_xor(v, 1));
    v = fmaxf(v, __shfl_xor(v, 2));
    v = fmaxf(v, __shfl_xor(v, 4));
    v = fmaxf(v, __shfl_xor(v, 8));
    rmax[i] = v;
  }
  if (l16 == 0) {
#pragma unroll
    for (int rt = 0; rt < 4; ++rt)
#pragma unroll
      for (int r = 0; r < 4; ++r)
        smax[wc][wr * 64 + rt * 16 + quad * 4 + r] = rmax[rt * 4 + r];
  }
  __syncthreads();
  if (tid < 128) {
    const float v = fmaxf(smax[0][tid], smax[1][tid]);
    pmax[(size_t)(qrow0 + tid) * NCHUNK + ychunk] = v;
  }
}

// ------- Kernel C: reduce partials; uniform row OR exact fp32 re-check -----
__global__ __launch_bounds__(256) void decide_kernel(
    const float* __restrict__ pmax, const float* __restrict__ qe,
    const float* __restrict__ me, const float* __restrict__ labels,
    float* __restrict__ out) {
  const int q = blockIdx.x;
  const int t = threadIdx.x;  // 256
  __shared__ float smx;
  if (t < 64) {
    float v = pmax[(size_t)q * NCHUNK + t];  // NCHUNK == 64
#pragma unroll
    for (int m = 1; m < 64; m <<= 1) v = fmaxf(v, __shfl_xor(v, m));
    if (t == 0) smx = v;
  }
  __syncthreads();
  if (smx <= 0.5f) {  // uniform fast path (expected for all queries)
    if (t < CN) out[(size_t)q * CN + t] = 1.0f / 128.0f;
    return;
  }
  // exact fp32 path (rare / borderline queries only)
  __shared__ float sred[256];
  __shared__ int sidx[256];
  __shared__ float wsum[4];
  const float* qr = qe + (size_t)q * DN;
  float ss = 0.f;
  for (int i = t; i < DN; i += 256) ss += qr[i] * qr[i];
#pragma unroll
  for (int m = 1; m < 64; m <<= 1) ss += __shfl_xor(ss, m);
  if ((t & 63) == 0) wsum[t >> 6] = ss;
  __syncthreads();
  const float qnorm = fmaxf(sqrtf(wsum[0] + wsum[1] + wsum[2] + wsum[3]), 1e-8f);

  float best = -3.0e38f;
  int bidx = 0x7fffffff;
  for (int j = t; j < MN; j += 256) {
    const float* mr = me + (size_t)j * DN;
    float dot = 0.f, ms = 0.f;
    for (int k = 0; k < DN; ++k) {
      float a = qr[k], b = mr[k];
      dot += a * b;
      ms += b * b;
    }
    const float sim = dot / (qnorm * fmaxf(sqrtf(ms), 1e-8f));
    if (sim > best) { best = sim; bidx = j; }  // strict > keeps first index
  }
  sred[t] = best;
  sidx[t] = bidx;
  __syncthreads();
  for (int s = 128; s > 0; s >>= 1) {
    if (t < s) {
      const float ov = sred[t + s];
      const int oi = sidx[t + s];
      if (ov > sred[t] || (ov == sred[t] && oi < sidx[t])) {
        sred[t] = ov;
        sidx[t] = oi;
      }
    }
    __syncthreads();
  }
  const float mx = sred[0];
  const int mi = sidx[0];
  if (t < CN)
    out[(size_t)q * CN + t] =
        (mx > 0.7f) ? labels[(size_t)mi * CN + t] : (1.0f / 128.0f);
}

extern "C" void kernel_launch(void* const* d_in, const int* in_sizes, int n_in,
                              void* d_out, int out_size, void* d_ws,
                              size_t ws_size, hipStream_t stream) {
  const float* qe = (const float*)d_in[0];  // [4096,384] f32
  const float* me = (const float*)d_in[1];  // [65536,384] f32
  const float* lb = (const float*)d_in[2];  // [65536,128] f32
  float* out = (float*)d_out;               // [4096,128] f32

  char* ws = (char*)d_ws;
  const size_t OFF_QN = 0;                  // qn4: 4096*192 = 786,432 B
  const size_t OFF_MN = OFF_QN + (size_t)QN * DN;        // mn4: 65536*192 B
  const size_t OFF_PMAX = OFF_MN + (size_t)MN * DN;      // (offsets roomy)
  unsigned char* qn4 = (unsigned char*)(ws + OFF_QN);    // fp4 fragment-major
  unsigned char* mn4 = (unsigned char*)(ws + OFF_MN);    // fp4 fragment-major
  float* pmax = (float*)(ws + OFF_PMAX);                 // [4096][64] = 1 MB

  nrm_kernel<<<(QN + MN) / 4, 256, 0, stream>>>(qe, me, qn4, mn4);
  gemm_max_kernel<<<dim3(QN / 128, NCHUNK), 256, 0, stream>>>(qn4, mn4, pmax);
  decide_kernel<<<QN, 256, 0, stream>>>(pmax, qe, me, lb, out);
}